// Round 3
// baseline (227.781 us; speedup 1.0000x reference)
//
#include <hip/hip_runtime.h>
#include <math.h>

#define H 2048
#define V 50257
#define S 2048

__device__ inline float dot4(float4 a, float4 b) {
  return a.x * b.x + a.y * b.y + a.z * b.z + a.w * b.w;
}

__device__ inline float wave_sum(float v) {
#pragma unroll
  for (int o = 32; o > 0; o >>= 1) v += __shfl_down(v, o, 64);
  return v;
}

__device__ inline float wave_max(float v) {
#pragma unroll
  for (int o = 32; o > 0; o >>= 1) v = fmaxf(v, __shfl_down(v, o, 64));
  return v;
}

// One block (256 threads) per output unit i: 6 dot products of length H.
__global__ __launch_bounds__(256) void gru_kernel(
    const float* __restrict__ w_ih, const float* __restrict__ w_hh,
    const float* __restrict__ b_ih, const float* __restrict__ b_hh,
    const float* __restrict__ x_base, const int* __restrict__ word,
    const float* __restrict__ hprev,
    float* __restrict__ hout_ws, float* __restrict__ hout_d) {
  const float* x = word ? (x_base + (size_t)word[0] * H) : x_base;
  const int i = blockIdx.x;
  const int t = threadIdx.x;
  const float4* x4 = (const float4*)x;
  const float4* h4 = (const float4*)hprev;
  float acc[6];
#pragma unroll
  for (int d = 0; d < 6; d++) acc[d] = 0.f;
#pragma unroll
  for (int g = 0; g < 3; g++) {
    const float4* wi = (const float4*)(w_ih + (size_t)(g * H + i) * H);
    const float4* wh = (const float4*)(w_hh + (size_t)(g * H + i) * H);
    float4 xa = x4[t], xb = x4[t + 256];
    float4 ha = h4[t], hb = h4[t + 256];
    acc[g]     = dot4(wi[t], xa) + dot4(wi[t + 256], xb);
    acc[3 + g] = dot4(wh[t], ha) + dot4(wh[t + 256], hb);
  }
  __shared__ float red[6][4];
  const int lane = t & 63, wid = t >> 6;
#pragma unroll
  for (int d = 0; d < 6; d++) {
    float s = wave_sum(acc[d]);
    if (lane == 0) red[d][wid] = s;
  }
  __syncthreads();
  if (t == 0) {
    float gi_r = red[0][0] + red[0][1] + red[0][2] + red[0][3] + b_ih[i];
    float gi_z = red[1][0] + red[1][1] + red[1][2] + red[1][3] + b_ih[H + i];
    float gi_n = red[2][0] + red[2][1] + red[2][2] + red[2][3] + b_ih[2 * H + i];
    float gh_r = red[3][0] + red[3][1] + red[3][2] + red[3][3] + b_hh[i];
    float gh_z = red[4][0] + red[4][1] + red[4][2] + red[4][3] + b_hh[H + i];
    float gh_n = red[5][0] + red[5][1] + red[5][2] + red[5][3] + b_hh[2 * H + i];
    float r = 1.f / (1.f + expf(-(gi_r + gh_r)));
    float z = 1.f / (1.f + expf(-(gi_z + gh_z)));
    float n = tanhf(gi_n + r * gh_n);
    float h = (1.f - z) * n + z * hprev[i];
    hout_ws[i] = h;
    hout_d[i] = h;
  }
}

// part[jt][k] = sum_{j in tile jt} coef[j] * mat[j][k].  grid=(8, 32), 64 rows/tile.
__global__ __launch_bounds__(256) void colsum_part_kernel(
    const float* __restrict__ mat, const float* __restrict__ coef,
    float* __restrict__ part) {
  const int k = blockIdx.x * 256 + threadIdx.x;
  const int jt = blockIdx.y;
  const int j0 = jt * 64;
  float acc = 0.f;
#pragma unroll 4
  for (int j = j0; j < j0 + 64; j++)
    acc += coef[j] * mat[(size_t)j * H + k];
  part[(size_t)jt * H + k] = acc;
}

// out[k] = sum over 32 partial tiles.  grid = 8 blocks x 256.
__global__ __launch_bounds__(256) void combine_kernel(
    const float* __restrict__ part, float* __restrict__ out) {
  const int k = blockIdx.x * 256 + threadIdx.x;
  float acc = 0.f;
#pragma unroll
  for (int jt = 0; jt < 32; jt++) acc += part[(size_t)jt * H + k];
  out[k] = acc;
}

// e[row] = dot(enc[row], v).  One wave per row, 4 rows per block.
__global__ __launch_bounds__(256) void energies_kernel(
    const float* __restrict__ enc, const float* __restrict__ v,
    float* __restrict__ e) {
  const int wid = threadIdx.x >> 6, lane = threadIdx.x & 63;
  const int row = blockIdx.x * 4 + wid;
  const float4* r4 = (const float4*)(enc + (size_t)row * H);
  const float4* v4 = (const float4*)v;
  float acc = 0.f;
#pragma unroll
  for (int k = 0; k < 8; k++) {
    int idx = lane + 64 * k;
    acc += dot4(r4[idx], v4[idx]);
  }
  acc = wave_sum(acc);
  if (lane == 0) e[row] = acc;
}

// Fused: redundant per-block softmax stats over e[0:2048], then partial
// context colsum for this block's 64-row tile. Blocks with jt==0 write attn.
__global__ __launch_bounds__(256) void softmax_ctx_part_kernel(
    const float* __restrict__ enc, const float* __restrict__ e,
    float* __restrict__ part, float* __restrict__ attn_out) {
  const int t = threadIdx.x;
  const int kb = blockIdx.x;   // 0..7  (k tile)
  const int jt = blockIdx.y;   // 0..31 (row tile)
  const int lane = t & 63, wid = t >> 6;
  __shared__ float sred[4];
  __shared__ float wtile[64];
  float ev[8];
  float m = -INFINITY;
#pragma unroll
  for (int r = 0; r < 8; r++) {
    ev[r] = e[t + 256 * r];
    m = fmaxf(m, ev[r]);
  }
  float mw = wave_max(m);
  if (lane == 0) sred[wid] = mw;
  __syncthreads();
  const float M = fmaxf(fmaxf(sred[0], sred[1]), fmaxf(sred[2], sred[3]));
  float s = 0.f;
#pragma unroll
  for (int r = 0; r < 8; r++) s += expf(ev[r] - M);
  float sw = wave_sum(s);
  __syncthreads();
  if (lane == 0) sred[wid] = sw;
  __syncthreads();
  const float inv = 1.f / (sred[0] + sred[1] + sred[2] + sred[3]);
  const int j0 = jt * 64;
  if (t < 64) wtile[t] = expf(e[j0 + t] - M) * inv;
  __syncthreads();
  if (jt == 0) {
    const int s_idx = kb * 256 + t;
    attn_out[s_idx] = expf(e[s_idx] - M) * inv;
  }
  const int k = kb * 256 + t;
  float acc = 0.f;
#pragma unroll 4
  for (int j = 0; j < 64; j++)
    acc += wtile[j] * enc[(size_t)(j0 + j) * H + k];
  part[(size_t)jt * H + k] = acc;
}

// logits[row] = dot(w_out[row], u) + b_out[row]; also per-block (max, sumexp).
__global__ __launch_bounds__(256) void logits_kernel(
    const float* __restrict__ w_out, const float* __restrict__ b_out,
    const float* __restrict__ u, float* __restrict__ logits,
    float* __restrict__ pairs) {
  const int wid = threadIdx.x >> 6, lane = threadIdx.x & 63;
  const int row = blockIdx.x * 4 + wid;
  __shared__ float lvals[4];
  float logit = -INFINITY;
  if (row < V) {
    const float4* r4 = (const float4*)(w_out + (size_t)row * (2 * H));
    const float4* u4 = (const float4*)u;
    float acc = 0.f;
#pragma unroll
    for (int k = 0; k < 16; k++) {
      int idx = lane + 64 * k;
      acc += dot4(r4[idx], u4[idx]);
    }
    acc = wave_sum(acc);
    logit = acc + b_out[row];
    if (lane == 0) logits[row] = logit;
  }
  if (lane == 0) lvals[wid] = logit;
  __syncthreads();
  if (threadIdx.x == 0) {
    float M = fmaxf(fmaxf(lvals[0], lvals[1]), fmaxf(lvals[2], lvals[3]));
    float sumexp = expf(lvals[0] - M) + expf(lvals[1] - M) +
                   expf(lvals[2] - M) + expf(lvals[3] - M);
    pairs[2 * blockIdx.x] = M;
    pairs[2 * blockIdx.x + 1] = sumexp;
  }
}

// Combine per-block (max,sumexp) pairs -> global logsumexp; subtract in place.
__global__ __launch_bounds__(1024) void lse_final_kernel(
    const float* __restrict__ pairs, int npairs, float* __restrict__ out) {
  const int t = threadIdx.x;
  const int lane = t & 63, wid = t >> 6;
  __shared__ float sm[16], ss[16];
  __shared__ float fin;
  float M = -INFINITY, Ssum = 0.f;
  for (int i = t; i < npairs; i += 1024) {
    float mb = pairs[2 * i], sb = pairs[2 * i + 1];
    float Mn = fmaxf(M, mb);
    Ssum = Ssum * expf(M - Mn) + sb * expf(mb - Mn);
    M = Mn;
  }
#pragma unroll
  for (int o = 32; o > 0; o >>= 1) {
    float mo = __shfl_down(M, o, 64);
    float so = __shfl_down(Ssum, o, 64);
    float Mn = fmaxf(M, mo);
    Ssum = Ssum * expf(M - Mn) + so * expf(mo - Mn);
    M = Mn;
  }
  if (lane == 0) { sm[wid] = M; ss[wid] = Ssum; }
  __syncthreads();
  if (t == 0) {
    float Mg = -INFINITY, Sg = 0.f;
    for (int i = 0; i < 16; i++) {
      float Mn = fmaxf(Mg, sm[i]);
      Sg = Sg * expf(Mg - Mn) + ss[i] * expf(sm[i] - Mn);
      Mg = Mn;
    }
    fin = Mg + logf(Sg);
  }
  __syncthreads();
  const float c = fin;
  for (int i = t; i < V; i += 1024) out[i] -= c;
}

extern "C" void kernel_launch(void* const* d_in, const int* in_sizes, int n_in,
                              void* d_out, int out_size, void* d_ws, size_t ws_size,
                              hipStream_t stream) {
  const int*   word  = (const int*)d_in[0];
  const float* lasth = (const float*)d_in[1];   // (2,1,H)
  const float* enc   = (const float*)d_in[2];   // (S,1,H) -> S x H
  const float* emb   = (const float*)d_in[3];   // (V,H)
  const float* w_ih0 = (const float*)d_in[4];
  const float* w_hh0 = (const float*)d_in[5];
  const float* b_ih0 = (const float*)d_in[6];
  const float* b_hh0 = (const float*)d_in[7];
  const float* w_ih1 = (const float*)d_in[8];
  const float* w_hh1 = (const float*)d_in[9];
  const float* b_ih1 = (const float*)d_in[10];
  const float* b_hh1 = (const float*)d_in[11];
  const float* wa    = (const float*)d_in[12];
  // d_in[13] = ba: constant across s -> cancels in softmax.
  const float* w_out = (const float*)d_in[14];
  const float* b_out = (const float*)d_in[15];

  float* out      = (float*)d_out;            // [0:V)        log_softmax
  float* h0_out   = out + V;                  // hidden[0]
  float* h1_out   = out + V + H;              // hidden[1]
  float* attn_out = out + V + 2 * H;          // attn weights (S)

  float* wsf   = (float*)d_ws;
  float* part  = wsf;                // 32 * H = 65536
  float* v     = wsf + 65536;        // H
  float* e     = wsf + 67584;        // S
  float* u     = wsf + 69632;        // 2H: [h1 | context]
  float* h0    = wsf + 73728;        // H
  float* pairs = wsf + 75776;        // 2 * 12565

  const int nblk = (V + 3) / 4;      // 12565

  gru_kernel<<<H, 256, 0, stream>>>(w_ih0, w_hh0, b_ih0, b_hh0, emb, word,
                                    lasth, h0, h0_out);
  gru_kernel<<<H, 256, 0, stream>>>(w_ih1, w_hh1, b_ih1, b_hh1, h0, nullptr,
                                    lasth + H, u, h1_out);
  colsum_part_kernel<<<dim3(8, 32), 256, 0, stream>>>(wa, u, part);
  combine_kernel<<<8, 256, 0, stream>>>(part, v);
  energies_kernel<<<S / 4, 256, 0, stream>>>(enc, v, e);
  softmax_ctx_part_kernel<<<dim3(8, 32), 256, 0, stream>>>(enc, e, part,
                                                           attn_out);
  combine_kernel<<<8, 256, 0, stream>>>(part, u + H);
  logits_kernel<<<nblk, 256, 0, stream>>>(w_out, b_out, u, out, pairs);
  lse_final_kernel<<<1, 1024, 0, stream>>>(pairs, nblk, out);
}